// Round 8
// baseline (1789.882 us; speedup 1.0000x reference)
//
#include <hip/hip_runtime.h>
#include <hip/hip_bf16.h>
#include <math.h>

#define NROWS 131072
#define ACT_D 12
#define COND_D 256
#define KEMB 256
#define EDIM 16
#define H1D 512
#define H2D 256
#define NB 16384

typedef __attribute__((ext_vector_type(8))) _Float16 half8;
typedef __attribute__((ext_vector_type(4))) float floatx4;
typedef unsigned short ushort_t;

#define LO_SCALE 4096.0f
#define INV_LO_SCALE 2.44140625e-4f

// ---------------------------------------------------------------------------
// Memory plan (unchanged).
// d_ws:
//   counts @ 0        (256 ints)
//   stats  @ 256      (1536 ints)
//   P2     @ 1792     : h2hi/h2lo -> d1hi/d1lo (f16 pairs)
//   P1     @ 33556224 : h1hi/h1lo -> distT(fp32) -> d2hi/d2lo
// d_out outRec region hosts converted transposed hi/lo-split weights until D2.
//
// Numerics: fp32 a = hi + lo*2^-12, hi=f16(a), lo=f16((a-hi)*4096).
// A@B = AhiBhi (accH) + (AhiBlo'+Alo'Bhi) (accX), out = accH + accX*2^-12.
//
// GEMM v8: v7's B-reg double-buffer WITHOUT the occupancy cliff.
// R7 post-mortem: v5 sat exactly at 64 VGPR + 64 AGPR = 128 = 4 waves/SIMD;
// v7's +4 VGPR dropped to 3 waves (33%) and regressed. Fix: BM=32 (wave =
// 32 rows x 32 cols) -> acc = 8 floatx4 = 32 AGPR (was 64), freeing room for
// the 4-uint4 B-next buffer. All next-tile work (1 A-DMA/wave + 4 B-loads
// into separate named regs) issues BEFORE compute; the barrier drain finds
// loads landed. LDS volume per output unchanged; TCP B-traffic 2x (still
// under the MFMA floor). MFMA fragments / K-order / 3-term structure
// identical to v5 -> bitwise-same outputs.
// ---------------------------------------------------------------------------

__global__ void init_kernel(int* counts, float* outScal) {
    int t = threadIdx.x;
    counts[t] = 0;
    if (t < 5) outScal[t] = 0.0f;
}

__device__ inline ushort_t f16bits(_Float16 h) { return __builtin_bit_cast(ushort_t, h); }
__device__ inline float f16pair(ushort_t a, ushort_t b) {
    return (float)__builtin_bit_cast(_Float16, a)
         + (float)__builtin_bit_cast(_Float16, b) * INV_LO_SCALE;
}
__device__ inline void splitf(float v, ushort_t& hi, ushort_t& lo) {
    _Float16 h = (_Float16)v;
    _Float16 l = (_Float16)((v - (float)h) * LO_SCALE);
    hi = f16bits(h); lo = f16bits(l);
}

__device__ inline void gload_lds16(const void* g, void* lds) {
    __builtin_amdgcn_global_load_lds((const __attribute__((address_space(1))) void*)g,
                                     (__attribute__((address_space(3))) void*)lds, 16, 0, 0);
}

// ---------------------------------------------------------------------------
// Weight conversion: W [K,N] fp32 -> Whi/Wlo [N,Kp] f16 (transposed, padded).
// ---------------------------------------------------------------------------
__global__ __launch_bounds__(256)
void convw_kernel(const float* __restrict__ W, ushort_t* __restrict__ Whi,
                  ushort_t* __restrict__ Wlo, int K, int N, int Kp)
{
    int n = blockIdx.x;
    int k = blockIdx.y * 256 + threadIdx.x;
    if (k >= Kp) return;
    float v = (k < K) ? W[(long)k * N + n] : 0.0f;
    ushort_t h, l; splitf(v, h, l);
    Whi[(long)n * Kp + k] = h;
    Wlo[(long)n * Kp + k] = l;
}

// ---------------------------------------------------------------------------
// f16x3 (scaled-lo) MFMA GEMM + bias + ELU.  C = elu(A @ W + b).
// BM=32, BN=128, BK=32, 256 thr (4 waves; wave w owns rows 0..31 x cols
// [w*32, w*32+32)).  A: LDS double-buffer (1 DMA/wave/step).  B: direct
// per-lane global_load_dwordx4 from L2, register double-buffered.
// LDS (uints), per buffer 1024:
//   Ahi [0,512):  k-quad q at q*128 + row*4   (32 rows x 16B)
//   Alo [512,1024)
// MFMA mappings (m89/m120-verified): A[m=lane&15][k=quad*8+j],
// B[k=quad*8+j][n=lane&15], C col=lane&15 row=quad*4+reg.
// ---------------------------------------------------------------------------
template<int CONCAT>
__global__ __launch_bounds__(256, 4)
void gemm_f16x3_kernel(const void* A0v, const void* A1v,
                       const ushort_t* __restrict__ Bhi, const ushort_t* __restrict__ Blo,
                       const float* __restrict__ bias,
                       ushort_t* __restrict__ Chi, ushort_t* __restrict__ Clo,
                       int Nw, int Kp, int Kvalid)
{
    __shared__ uint lds[2048];            // 2 buffers x 1024 uints (2 x 4 KB, A only)
    const int tid = threadIdx.x;
    const int w = tid >> 6, l = tid & 63;
    const int quad = l >> 4, lr = l & 15;
    const long rowBase = (long)blockIdx.x * 32;
    const int colBase = blockIdx.y * 128;
    const int nQ = w * 32;

    floatx4 accH[2][2], accX[2][2];
#pragma unroll
    for (int i = 0; i < 2; ++i)
#pragma unroll
        for (int j = 0; j < 2; ++j) { accH[i][j] = (floatx4)(0.0f); accX[i][j] = (floatx4)(0.0f); }

    // ---- B fragment offsets (32-bit, per lane; SGPR base + voffset form) ----
    const uint off0 = (uint)((colBase + nQ + lr) * Kp + quad * 8);
    const uint off1 = off0 + (uint)(16 * Kp);

    uint4 bch0, bch1, bcl0, bcl1;                   // CURRENT-tile B (named)
    uint4 bnh0, bnh1, bnl0, bnl1;                   // NEXT-tile B (named)
    auto loadBcur = [&](int k0) {
        bch0 = *(const uint4*)(Bhi + off0 + k0);
        bch1 = *(const uint4*)(Bhi + off1 + k0);
        bcl0 = *(const uint4*)(Blo + off0 + k0);
        bcl1 = *(const uint4*)(Blo + off1 + k0);
    };
    auto loadBnext = [&](int k0) {
        bnh0 = *(const uint4*)(Bhi + off0 + k0);
        bnh1 = *(const uint4*)(Bhi + off1 + k0);
        bnl0 = *(const uint4*)(Blo + off0 + k0);
        bnl1 = *(const uint4*)(Blo + off1 + k0);
    };
    auto promoteB = [&]() {
        bch0 = bnh0; bch1 = bnh1; bcl0 = bnl0; bcl1 = bnl1;
    };

    // ---- A staging, DMA path (CONCAT==0): A pre-split f16 hi/lo, [M,Kp].
    // Wave w covers: w0 hi-quads 0/1, w1 hi-quads 2/3, w2 lo-q0/1, w3 lo-q2/3.
    // Lane l -> LDS uint (l*4) within the wave's 256-uint span = [q][row][4].
    const ushort_t* aSrc = (const ushort_t*)((w < 2) ? A0v : A1v);
    const ushort_t* pAdma = aSrc + (rowBase + (l & 31)) * Kp
                                 + ((w & 1) * 2 + (l >> 5)) * 8;
    const int ldsWaveBase = (w >> 1) * 512 + (w & 1) * 256;
    auto stageA0 = [&](int buf, int k0) {
        gload_lds16(pAdma + k0, &lds[buf * 1024 + ldsWaveBase]);
    };

    // ---- A staging, fp32-concat path (CONCAT!=0): 1 float4/thread.
    // Thread t: row r = t>>3, seg = t&7 (k = seg*4..seg*4+3).
    const float* A1p = (const float*)A0v;
    const float* A2p = (const float*)A1v;
    const int cr = tid >> 3, cseg = tid & 7;
    const long crow = rowBase + cr;
    const int cwOff = (cseg >> 1) * 128 + cr * 4 + (cseg & 1) * 2;  // hi uint offset

    float v[4];
    auto cload = [&](int k0) {
        const int kk = k0 + cseg * 4;
        if (kk >= CONCAT && kk + 4 <= Kvalid) {
            *(float4*)v = *(const float4*)(A2p + crow * COND_D + (kk - CONCAT));
        } else if (kk + 4 <= CONCAT) {
            *(float4*)v = *(const float4*)(A1p + crow * CONCAT + kk);
        } else {
#pragma unroll
            for (int i = 0; i < 4; ++i) {
                int k = kk + i;
                v[i] = (k < CONCAT) ? A1p[crow * CONCAT + k]
                     : (k < Kvalid) ? A2p[crow * COND_D + (k - CONCAT)] : 0.0f;
            }
        }
    };
    auto cwrite = [&](int buf) {
        ushort_t h0, l0, h1, l1, h2, l2, h3, l3;
        splitf(v[0], h0, l0); splitf(v[1], h1, l1);
        splitf(v[2], h2, l2); splitf(v[3], h3, l3);
        uint2 hh, ll;
        hh.x = (uint)h0 | ((uint)h1 << 16); hh.y = (uint)h2 | ((uint)h3 << 16);
        ll.x = (uint)l0 | ((uint)l1 << 16); ll.y = (uint)l2 | ((uint)l3 << 16);
        *(uint2*)&lds[buf * 1024 + cwOff]       = hh;
        *(uint2*)&lds[buf * 1024 + 512 + cwOff] = ll;
    };

    // ---- compute: A from LDS, B from current regs (12 MFMA/wave/step) ----
    auto compute = [&](int buf) {
        const int base = buf * 1024;
        half8 bh0 = __builtin_bit_cast(half8, bch0);
        half8 bh1 = __builtin_bit_cast(half8, bch1);
        half8 bl0 = __builtin_bit_cast(half8, bcl0);
        half8 bl1 = __builtin_bit_cast(half8, bcl1);
#pragma unroll
        for (int im = 0; im < 2; ++im) {
            int aoff = base + quad * 128 + (im * 16 + lr) * 4;
            half8 ah = __builtin_bit_cast(half8, *(uint4*)&lds[aoff]);
            half8 al = __builtin_bit_cast(half8, *(uint4*)&lds[aoff + 512]);
            accH[im][0] = __builtin_amdgcn_mfma_f32_16x16x32_f16(ah, bh0, accH[im][0], 0, 0, 0);
            accX[im][0] = __builtin_amdgcn_mfma_f32_16x16x32_f16(ah, bl0, accX[im][0], 0, 0, 0);
            accX[im][0] = __builtin_amdgcn_mfma_f32_16x16x32_f16(al, bh0, accX[im][0], 0, 0, 0);
            accH[im][1] = __builtin_amdgcn_mfma_f32_16x16x32_f16(ah, bh1, accH[im][1], 0, 0, 0);
            accX[im][1] = __builtin_amdgcn_mfma_f32_16x16x32_f16(ah, bl1, accX[im][1], 0, 0, 0);
            accX[im][1] = __builtin_amdgcn_mfma_f32_16x16x32_f16(al, bh1, accX[im][1], 0, 0, 0);
        }
    };

    const int kTiles = Kp / 32;
    int cur = 0;

    // ---- prologue: tile 0 -> buffer 0 / current B regs ----
    if constexpr (CONCAT == 0) {
        stageA0(0, 0);
        loadBcur(0);
        __syncthreads();                    // drains DMA + publishes buf0
    } else {
        cload(0);
        loadBcur(0);
        cwrite(0);                          // waits for cload regs
        __syncthreads();
    }

    // ---- main loop: ALL next-tile loads issued BEFORE compute ----
    for (int t = 0; t < kTiles; ++t) {
        const bool hasNext = (t + 1 < kTiles);
        const int k0n = (t + 1) * 32;
        if constexpr (CONCAT == 0) {
            if (hasNext) {
                stageA0(cur ^ 1, k0n);      // A[t+1] DMA in flight during compute
                loadBnext(k0n);             // B[t+1] -> separate regs, in flight
            }
            compute(cur);                   // no waits: cur A (LDS) + cur B regs
        } else {
            if (hasNext) {
                cload(k0n);                 // A[t+1] fp32 -> regs (oldest)
                loadBnext(k0n);             // B[t+1] (newer)
            }
            compute(cur);
            if (hasNext) cwrite(cur ^ 1);   // waits cload only (landed under compute)
        }
        __syncthreads();                    // drain finds loads already landed
        if (hasNext) promoteB();
        cur ^= 1;
    }

    // ---- epilogue: combine, bias, ELU, hi/lo split store ----
    float bv[2];
#pragma unroll
    for (int jn = 0; jn < 2; ++jn) bv[jn] = bias[colBase + nQ + jn * 16 + lr];
#pragma unroll
    for (int im = 0; im < 2; ++im) {
#pragma unroll
        for (int jn = 0; jn < 2; ++jn) {
            int n = colBase + nQ + jn * 16 + lr;
#pragma unroll
            for (int rr = 0; rr < 4; ++rr) {
                long m = rowBase + im * 16 + quad * 4 + rr;
                float x = accH[im][jn][rr] + accX[im][jn][rr] * INV_LO_SCALE + bv[jn];
                x = x > 0.0f ? x : (expf(x) - 1.0f);
                ushort_t h, lo; splitf(x, h, lo);
                long idx = m * Nw + n;
                Chi[idx] = h;
                Clo[idx] = lo;
            }
        }
    }
}

// ---------------------------------------------------------------------------
// K3: z = h2@W3+b3 (fp32, h2 = hi + lo*2^-12), normalize, argmax,
// quantized -> d_out, q-latent partial, counts, distT (transposed) write.
// ---------------------------------------------------------------------------
__global__ __launch_bounds__(256)
void quantize_kernel(const ushort_t* __restrict__ h2hi, const ushort_t* __restrict__ h2lo,
                     const float* __restrict__ W3,
                     const float* __restrict__ b3, const float* __restrict__ emb,
                     float* __restrict__ distT, float* __restrict__ outQ,
                     float* __restrict__ outIdx, int* __restrict__ counts,
                     float* __restrict__ qsum)
{
    __shared__ float h2t[16 * 260];
    __shared__ float w3t[16 * 260];
    __shared__ float nwt[256 * 20];
    __shared__ float zt[16 * 17];
    __shared__ float dt[16 * 257];
    __shared__ int   lcnt[256];
    __shared__ float swred[4];

    int t = threadIdx.x;
    long rowBase = (long)blockIdx.x * 16;

    for (int it = 0; it < 16; ++it) {
        long idx = (rowBase + it) * 256 + t;
        h2t[it * 260 + t] = f16pair(h2hi[idx], h2lo[idx]);
    }
    for (int it = 0; it < 16; ++it) {
        int flat = it * 256 + t;
        int j = flat >> 4, c = flat & 15;
        w3t[c * 260 + j] = W3[flat];
    }
    {
        float e0[16]; float ss = 0.f;
#pragma unroll
        for (int i = 0; i < 16; ++i) { e0[i] = emb[t * 16 + i]; ss += e0[i] * e0[i]; }
        float inv = 1.0f / fmaxf(sqrtf(ss), 1e-12f);
#pragma unroll
        for (int i = 0; i < 16; ++i) nwt[t * 20 + i] = e0[i] * inv;
    }
    lcnt[t] = 0;
    __syncthreads();

    int r = t >> 4, c = t & 15;
    float zacc = b3[c];
    for (int j4 = 0; j4 < 64; ++j4) {
        float4 h = *(const float4*)&h2t[r * 260 + j4 * 4];
        float4 w = *(const float4*)&w3t[c * 260 + j4 * 4];
        zacc += h.x * w.x + h.y * w.y + h.z * w.z + h.w * w.w;
    }
    float ss = zacc * zacc;
#pragma unroll
    for (int m = 1; m < 16; m <<= 1) ss += __shfl_xor(ss, m, 64);
    zt[r * 17 + c] = zacc / fmaxf(sqrtf(ss), 1e-12f);
    __syncthreads();

    float zr[16];
#pragma unroll
    for (int e = 0; e < 16; ++e) zr[e] = zt[r * 17 + e];
    float best = -1e30f; int bidx = 0;
    for (int cc = 0; cc < 16; ++cc) {
        int col = cc * 16 + c;
        float d = 0.f;
#pragma unroll
        for (int e4 = 0; e4 < 4; ++e4) {
            float4 wv = *(const float4*)&nwt[col * 20 + e4 * 4];
            d += zr[e4 * 4 + 0] * wv.x + zr[e4 * 4 + 1] * wv.y
               + zr[e4 * 4 + 2] * wv.z + zr[e4 * 4 + 3] * wv.w;
        }
        dt[r * 257 + col] = d;
        if (d > best || (d == best && col < bidx)) { best = d; bidx = col; }
    }
#pragma unroll
    for (int m = 1; m < 16; m <<= 1) {
        float ov = __shfl_xor(best, m, 64);
        int   oi = __shfl_xor(bidx, m, 64);
        if (ov > best || (ov == best && oi < bidx)) { best = ov; bidx = oi; }
    }

    float q = emb[bidx * 16 + c];
    outQ[(rowBase + r) * 16 + c] = q;
    float df = q - zacc;
    float part = df * df;
#pragma unroll
    for (int m = 1; m < 64; m <<= 1) part += __shfl_xor(part, m, 64);
    if ((t & 63) == 0) swred[t >> 6] = part;
    if (c == 0) {
        outIdx[rowBase + r] = (float)bidx;
        atomicAdd(&lcnt[bidx], 1);
    }
    __syncthreads();
    if (t == 0) atomicAdd(qsum, swred[0] + swred[1] + swred[2] + swred[3]);
    if (lcnt[t] > 0) atomicAdd(&counts[t], lcnt[t]);

    int rr = t & 15, cg = t >> 4;
    for (int i = 0; i < 16; ++i) {
        int col = i * 16 + cg;
        distT[(long)col * NROWS + rowBase + rr] = dt[rr * 257 + col];
    }
}

// ---------------------------------------------------------------------------
// SelA: per-column histogram; median bin and top-512 threshold bin.
// ---------------------------------------------------------------------------
__global__ __launch_bounds__(1024)
void selA_kernel(const float* __restrict__ distT, int* __restrict__ stats)
{
    __shared__ int hist[NB];
    __shared__ int part[1024];
    int t = threadIdx.x, c = blockIdx.x;
    for (int i = t; i < NB; i += 1024) hist[i] = 0;
    __syncthreads();
    const float* col = distT + (long)c * NROWS;
    for (int i = t; i < NROWS; i += 1024) {
        float v = col[i];
        int b = (int)((v + 1.0f) * (NB * 0.5f));
        b = min(max(b, 0), NB - 1);
        atomicAdd(&hist[b], 1);
    }
    __syncthreads();
    const int CH = NB / 1024;
    int s = 0;
    for (int i = 0; i < CH; ++i) s += hist[t * CH + i];
    part[t] = s;
    __syncthreads();
    if (t == 0) {
        int target = NROWS / 2;
        int cum = 0; int chunk = 0;
        while (cum + part[chunk] < target) { cum += part[chunk]; ++chunk; }
        int b = chunk * CH;
        while (cum + hist[b] < target) { cum += hist[b]; ++b; }
        int medBin = b, needLow = target - cum, cntMed = hist[b];
        int cumA = 0; chunk = 1023;
        while (cumA + part[chunk] < 512) { cumA += part[chunk]; --chunk; }
        b = chunk * CH + CH - 1;
        while (cumA + hist[b] < 512) { cumA += hist[b]; --b; }
        int topBin = b, needTop = 512 - cumA, cntTop = hist[b];
        int* st = stats + c * 6;
        st[0] = medBin; st[1] = needLow; st[2] = cntMed;
        st[3] = topBin; st[4] = needTop; st[5] = cntTop;
    }
}

// ---------------------------------------------------------------------------
// SelB: re-scan column; top-512 mean and logsumexp over bottom half.
// ---------------------------------------------------------------------------
__global__ __launch_bounds__(1024)
void selB_kernel(const float* __restrict__ distT, const int* __restrict__ stats,
                 float* __restrict__ contra_sum)
{
    __shared__ float red[64];
    int t = threadIdx.x, c = blockIdx.x;
    const int* st = stats + c * 6;
    int medBin = st[0], needLow = st[1], cntMed = st[2];
    int topBin = st[3], needTop = st[4], cntTop = st[5];
    const float binw = 2.0f / NB;
    float mUp = -1.0f + (medBin + 1) * binw;
    const float INVT = 1.0f / 0.07f;
    const float* col = distT + (long)c * NROWS;
    float topS = 0.f, tbS = 0.f, lowS = 0.f, mbS = 0.f;
    for (int i = t; i < NROWS; i += 1024) {
        float v = col[i];
        int b = (int)((v + 1.0f) * (NB * 0.5f));
        b = min(max(b, 0), NB - 1);
        if (b > topBin)       topS += v;
        else if (b == topBin) tbS += v;
        if (b < medBin)       lowS += expf((v - mUp) * INVT);
        else if (b == medBin) mbS  += expf((v - mUp) * INVT);
    }
#pragma unroll
    for (int m = 1; m < 64; m <<= 1) {
        topS += __shfl_xor(topS, m, 64);
        tbS  += __shfl_xor(tbS, m, 64);
        lowS += __shfl_xor(lowS, m, 64);
        mbS  += __shfl_xor(mbS, m, 64);
    }
    if ((t & 63) == 0) {
        int wv = t >> 6;
        red[wv * 4 + 0] = topS; red[wv * 4 + 1] = tbS;
        red[wv * 4 + 2] = lowS; red[wv * 4 + 3] = mbS;
    }
    __syncthreads();
    if (t == 0) {
        float T0 = 0, T1 = 0, T2 = 0, T3 = 0;
        for (int wv = 0; wv < 16; ++wv) {
            T0 += red[wv * 4 + 0]; T1 += red[wv * 4 + 1];
            T2 += red[wv * 4 + 2]; T3 += red[wv * 4 + 3];
        }
        float dis_pos = (T0 + needTop * (T1 / cntTop)) * (1.0f / 512.0f);
        float S = T2 + needLow * (T3 / cntMed);
        float colContra = log1pf(S * expf((mUp - dis_pos) * INVT));
        atomicAdd(contra_sum, colContra);
    }
}

// ---------------------------------------------------------------------------
// D3: reconstructed = d2 @ dec_w3 + b (d2 = hi + lo*2^-12), + recon loss.
// ---------------------------------------------------------------------------
__global__ __launch_bounds__(256)
void dec3_kernel(const ushort_t* __restrict__ d2hi, const ushort_t* __restrict__ d2lo,
                 const float* __restrict__ W,
                 const float* __restrict__ bias, const float* __restrict__ actions,
                 float* __restrict__ rec, float* __restrict__ recon_sum)
{
    __shared__ float dtile[16 * 516];
    __shared__ float wt[512 * 12];
    __shared__ float red2[4];
    int t = threadIdx.x;
    long rowBase = (long)blockIdx.x * 16;
    for (int it = 0; it < 24; ++it) wt[it * 256 + t] = W[it * 256 + t];
    for (int it = 0; it < 32; ++it) {
        int flat = it * 256 + t;
        int r = flat >> 9, k = flat & 511;
        long idx = (rowBase + r) * 512 + k;
        dtile[r * 516 + k] = f16pair(d2hi[idx], d2lo[idx]);
    }
    __syncthreads();
    float part = 0.f;
    if (t < 192) {
        int r = t / 12, cc = t % 12;
        float acc = bias[cc];
        for (int k4 = 0; k4 < 128; ++k4) {
            float4 h = *(const float4*)&dtile[r * 516 + k4 * 4];
            acc += h.x * wt[(k4 * 4 + 0) * 12 + cc] + h.y * wt[(k4 * 4 + 1) * 12 + cc]
                 + h.z * wt[(k4 * 4 + 2) * 12 + cc] + h.w * wt[(k4 * 4 + 3) * 12 + cc];
        }
        rec[(rowBase + r) * 12 + cc] = acc;
        float df = acc - actions[(rowBase + r) * 12 + cc];
        part = df * df;
    }
#pragma unroll
    for (int m = 1; m < 64; m <<= 1) part += __shfl_xor(part, m, 64);
    if ((t & 63) == 0) red2[t >> 6] = part;
    __syncthreads();
    if (t == 0) atomicAdd(recon_sum, red2[0] + red2[1] + red2[2] + red2[3]);
}

// ---------------------------------------------------------------------------
// finalize: perplexity from counts + scalar outputs.
// ---------------------------------------------------------------------------
__global__ void finalize_kernel(const int* __restrict__ counts, float* __restrict__ outScal)
{
    __shared__ float red[4];
    int t = threadIdx.x;
    float p = counts[t] * (1.0f / NROWS);
    float term = p * logf(p + 1e-10f);
#pragma unroll
    for (int m = 1; m < 64; m <<= 1) term += __shfl_xor(term, m, 64);
    if ((t & 63) == 0) red[t >> 6] = term;
    __syncthreads();
    if (t == 0) {
        float hsum = red[0] + red[1] + red[2] + red[3];
        float qsum = outScal[0], contra = outScal[2], recon = outScal[4];
        float ql = qsum * (1.0f / (NROWS * 16.0f));
        outScal[0] = ql;
        outScal[1] = 0.25f * ql;
        outScal[2] = contra * (1.0f / 256.0f);
        outScal[3] = expf(-hsum);
        outScal[4] = recon * (1.0f / (NROWS * 12.0f));
    }
}

extern "C" void kernel_launch(void* const* d_in, const int* in_sizes, int n_in,
                              void* d_out, int out_size, void* d_ws, size_t ws_size,
                              hipStream_t stream)
{
    const float* actions    = (const float*)d_in[0];
    const float* conditions = (const float*)d_in[1];
    const float* enc_w1 = (const float*)d_in[2];
    const float* enc_b1 = (const float*)d_in[3];
    const float* enc_w2 = (const float*)d_in[4];
    const float* enc_b2 = (const float*)d_in[5];
    const float* enc_w3 = (const float*)d_in[6];
    const float* enc_b3 = (const float*)d_in[7];
    const float* dec_w1 = (const float*)d_in[8];
    const float* dec_b1 = (const float*)d_in[9];
    const float* dec_w2 = (const float*)d_in[10];
    const float* dec_b2 = (const float*)d_in[11];
    const float* dec_w3 = (const float*)d_in[12];
    const float* dec_b3 = (const float*)d_in[13];
    const float* emb    = (const float*)d_in[14];

    float* out     = (float*)d_out;
    float* outRec  = out;
    float* outQ    = out + (long)NROWS * 12;
    float* outIdx  = out + (long)NROWS * 28;
    float* outScal = out + (long)NROWS * 29;

    // converted weights live in the (dead-until-dec3) outRec region
    ushort_t* wb    = (ushort_t*)d_out;
    ushort_t* w1hi  = wb;            ushort_t* w1lo  = wb + 147456;
    ushort_t* w2hi  = wb + 294912;   ushort_t* w2lo  = wb + 425984;
    ushort_t* wd1hi = wb + 557056;   ushort_t* wd1lo = wb + 630784;
    ushort_t* wd2hi = wb + 704512;   ushort_t* wd2lo = wb + 835584;

    float* ws = (float*)d_ws;
    int* counts = (int*)ws;
    int* stats  = (int*)(ws + 256);
    ushort_t* h2hi = (ushort_t*)(ws + 1792);
    ushort_t* h2lo = (ushort_t*)(ws + 16779008);
    ushort_t* d1hi = h2hi;
    ushort_t* d1lo = h2lo;
    float*    P1   = ws + 33556224;
    ushort_t* h1hi = (ushort_t*)P1;
    ushort_t* h1lo = (ushort_t*)(ws + 67110656);
    float*    distT = P1;
    ushort_t* d2hi = h1hi;
    ushort_t* d2lo = h1lo;

    hipLaunchKernelGGL(init_kernel, dim3(1), dim3(256), 0, stream, counts, outScal);
    hipLaunchKernelGGL(convw_kernel, dim3(512, 2), dim3(256), 0, stream, enc_w1, w1hi, w1lo, 268, 512, 288);
    hipLaunchKernelGGL(convw_kernel, dim3(256, 2), dim3(256), 0, stream, enc_w2, w2hi, w2lo, 512, 256, 512);
    hipLaunchKernelGGL(convw_kernel, dim3(256, 2), dim3(256), 0, stream, dec_w1, wd1hi, wd1lo, 272, 256, 288);
    hipLaunchKernelGGL(convw_kernel, dim3(512, 1), dim3(256), 0, stream, dec_w2, wd2hi, wd2lo, 256, 512, 256);
    // E1: h1 = elu(concat(actions,conditions) @ W1 + b1)
    hipLaunchKernelGGL((gemm_f16x3_kernel<ACT_D>), dim3(4096, 4), dim3(256), 0, stream,
                       (const void*)actions, (const void*)conditions, w1hi, w1lo, enc_b1,
                       h1hi, h1lo, H1D, 288, 268);
    // E2: h2 = elu(h1 @ W2 + b2)
    hipLaunchKernelGGL((gemm_f16x3_kernel<0>), dim3(4096, 2), dim3(256), 0, stream,
                       (const void*)h1hi, (const void*)h1lo, w2hi, w2lo, enc_b2,
                       h2hi, h2lo, H2D, 512, 512);
    // K3: z, normalize, argmax, quantized, counts, q-latent, distT
    hipLaunchKernelGGL(quantize_kernel, dim3(8192), dim3(256), 0, stream,
                       h2hi, h2lo, enc_w3, enc_b3, emb, distT, outQ, outIdx, counts, &outScal[0]);
    hipLaunchKernelGGL(selA_kernel, dim3(256), dim3(1024), 0, stream, distT, stats);
    hipLaunchKernelGGL(selB_kernel, dim3(256), dim3(1024), 0, stream, distT, stats, &outScal[2]);
    // D1: d1 = elu(concat(quantized,conditions) @ Wd1 + b1)
    hipLaunchKernelGGL((gemm_f16x3_kernel<EDIM>), dim3(4096, 2), dim3(256), 0, stream,
                       (const void*)outQ, (const void*)conditions, wd1hi, wd1lo, dec_b1,
                       d1hi, d1lo, H2D, 288, 272);
    // D2: d2 = elu(d1 @ Wd2 + b2)
    hipLaunchKernelGGL((gemm_f16x3_kernel<0>), dim3(4096, 4), dim3(256), 0, stream,
                       (const void*)d1hi, (const void*)d1lo, wd2hi, wd2lo, dec_b2,
                       d2hi, d2lo, H1D, 256, 256);
    // D3: reconstructed + loss
    hipLaunchKernelGGL(dec3_kernel, dim3(8192), dim3(256), 0, stream,
                       d2hi, d2lo, dec_w3, dec_b3, actions, outRec, &outScal[4]);
    hipLaunchKernelGGL(finalize_kernel, dim3(1), dim3(256), 0, stream, counts, outScal);
}

// Round 9
// 1479.925 us; speedup vs baseline: 1.2094x; 1.2094x over previous
//
#include <hip/hip_runtime.h>
#include <hip/hip_bf16.h>
#include <math.h>

#define NROWS 131072
#define ACT_D 12
#define COND_D 256
#define KEMB 256
#define EDIM 16
#define H1D 512
#define H2D 256
#define NB 16384

typedef __attribute__((ext_vector_type(8))) _Float16 half8;
typedef __attribute__((ext_vector_type(4))) float floatx4;
typedef unsigned short ushort_t;

#define LO_SCALE 4096.0f
#define INV_LO_SCALE 2.44140625e-4f

// ---------------------------------------------------------------------------
// Memory plan (unchanged).
// d_ws:
//   counts @ 0        (256 ints)
//   stats  @ 256      (1536 ints)
//   P2     @ 1792     : h2hi/h2lo -> d1hi/d1lo (f16 pairs)
//   P1     @ 33556224 : h1hi/h1lo -> distT(fp32) -> d2hi/d2lo
// d_out outRec region hosts converted transposed hi/lo-split weights until D2.
//
// Numerics: fp32 a = hi + lo*2^-12, hi=f16(a), lo=f16((a-hi)*4096).
// A@B = AhiBhi (accH) + (AhiBlo'+Alo'Bhi) (accX), out = accH + accX*2^-12.
//
// GEMM v9 = v5 (verified best: BM=64, A via LDS-DMA dbuf, B direct from L2,
// plain __syncthreads) + B-REGISTER DOUBLE-BUFFER where the reg budget
// allows. R7 measured: v5 sits at 64 VGPR + 64 AGPR = 128 = exactly 4
// waves/SIMD; the CONCAT!=0 instantiation (+concat machinery) overflowed to
// 68 with B-dbuf -> 3 waves -> regression. R8 measured: shrinking BM to pay
// for regs collapses per-step work below the latency it must hide. So:
// template<CONCAT,BDBUF>; E2/D2 (CONCAT==0, lean) get the B-dbuf schedule
// (loadBnext BEFORE compute -> barrier drain finds loads landed); E1/D1
// keep v5's schedule verbatim. B addressing in 32-bit-offset form (reg-cheap,
// v8-verified idiom) for extra headroom.
// ---------------------------------------------------------------------------

__global__ void init_kernel(int* counts, float* outScal) {
    int t = threadIdx.x;
    counts[t] = 0;
    if (t < 5) outScal[t] = 0.0f;
}

__device__ inline ushort_t f16bits(_Float16 h) { return __builtin_bit_cast(ushort_t, h); }
__device__ inline float f16pair(ushort_t a, ushort_t b) {
    return (float)__builtin_bit_cast(_Float16, a)
         + (float)__builtin_bit_cast(_Float16, b) * INV_LO_SCALE;
}
__device__ inline void splitf(float v, ushort_t& hi, ushort_t& lo) {
    _Float16 h = (_Float16)v;
    _Float16 l = (_Float16)((v - (float)h) * LO_SCALE);
    hi = f16bits(h); lo = f16bits(l);
}

__device__ inline void gload_lds16(const void* g, void* lds) {
    __builtin_amdgcn_global_load_lds((const __attribute__((address_space(1))) void*)g,
                                     (__attribute__((address_space(3))) void*)lds, 16, 0, 0);
}

// ---------------------------------------------------------------------------
// Weight conversion: W [K,N] fp32 -> Whi/Wlo [N,Kp] f16 (transposed, padded).
// ---------------------------------------------------------------------------
__global__ __launch_bounds__(256)
void convw_kernel(const float* __restrict__ W, ushort_t* __restrict__ Whi,
                  ushort_t* __restrict__ Wlo, int K, int N, int Kp)
{
    int n = blockIdx.x;
    int k = blockIdx.y * 256 + threadIdx.x;
    if (k >= Kp) return;
    float v = (k < K) ? W[(long)k * N + n] : 0.0f;
    ushort_t h, l; splitf(v, h, l);
    Whi[(long)n * Kp + k] = h;
    Wlo[(long)n * Kp + k] = l;
}

// ---------------------------------------------------------------------------
// f16x3 (scaled-lo) MFMA GEMM + bias + ELU.  C = elu(A @ W + b).
// BM=64, BN=128, BK=32, 256 thr (4 waves; wave w owns rows 0..63 x cols
// [w*32, w*32+32)).  A: LDS double-buffer.  B: direct per-lane
// global_load_dwordx4 from L2; register double-buffered iff BDBUF.
// LDS (uints), per buffer 2048:
//   Ahi [0,1024): k-quad q at q*256 + row*4    (64 rows x 16B)
//   Alo [1024,2048)
// MFMA mappings (m89/m120-verified): A[m=lane&15][k=quad*8+j],
// B[k=quad*8+j][n=lane&15], C col=lane&15 row=quad*4+reg.
// ---------------------------------------------------------------------------
template<int CONCAT, int BDBUF>
__global__ __launch_bounds__(256, 3)
void gemm_f16x3_kernel(const void* A0v, const void* A1v,
                       const ushort_t* __restrict__ Bhi, const ushort_t* __restrict__ Blo,
                       const float* __restrict__ bias,
                       ushort_t* __restrict__ Chi, ushort_t* __restrict__ Clo,
                       int Nw, int Kp, int Kvalid)
{
    __shared__ uint lds[4096];            // 2 buffers x 2048 uints (2 x 8 KB, A only)
    const int tid = threadIdx.x;
    const int w = tid >> 6, l = tid & 63;
    const int quad = l >> 4, lr = l & 15;
    const long rowBase = (long)blockIdx.x * 64;
    const int colBase = blockIdx.y * 128;
    const int nQ = w * 32;

    floatx4 accH[4][2], accX[4][2];
#pragma unroll
    for (int i = 0; i < 4; ++i)
#pragma unroll
        for (int j = 0; j < 2; ++j) { accH[i][j] = (floatx4)(0.0f); accX[i][j] = (floatx4)(0.0f); }

    // ---- B fragment offsets (32-bit voffset form; SGPR base + v_off) ----
    const uint off0 = (uint)((colBase + nQ + lr) * Kp + quad * 8);
    const uint off1 = off0 + (uint)(16 * Kp);

    uint4 bch0, bch1, bcl0, bcl1;                   // CURRENT-tile B (named)
    uint4 bnh0, bnh1, bnl0, bnl1;                   // NEXT-tile B (named, BDBUF only)
    auto loadBcur = [&](int k0) {
        bch0 = *(const uint4*)(Bhi + off0 + k0);
        bch1 = *(const uint4*)(Bhi + off1 + k0);
        bcl0 = *(const uint4*)(Blo + off0 + k0);
        bcl1 = *(const uint4*)(Blo + off1 + k0);
    };
    auto loadBnext = [&](int k0) {
        bnh0 = *(const uint4*)(Bhi + off0 + k0);
        bnh1 = *(const uint4*)(Bhi + off1 + k0);
        bnl0 = *(const uint4*)(Blo + off0 + k0);
        bnl1 = *(const uint4*)(Blo + off1 + k0);
    };
    auto promoteB = [&]() {
        bch0 = bnh0; bch1 = bnh1; bcl0 = bnl0; bcl1 = bnl1;
    };

    // ---- A staging, DMA path (CONCAT==0): A already f16 hi/lo, [M,Kp] ----
    const ushort_t* pAh = (const ushort_t*)A0v + (rowBase + l) * Kp + w * 8;
    const ushort_t* pAl = (const ushort_t*)A1v + (rowBase + l) * Kp + w * 8;
    auto stageA0 = [&](int buf, int k0) {
        uint* d = &lds[buf * 2048 + w * 256];
        gload_lds16(pAh + k0, d);
        gload_lds16(pAl + k0, d + 1024);
    };

    // ---- A staging, fp32-concat path (CONCAT!=0): load->regs, convert,
    //      ds_write (all compiler-scoreboarded; __syncthreads publishes). ----
    const float* A1p = (const float*)A0v;
    const float* A2p = (const float*)A1v;
    const long grow = rowBase + l;

    auto aload = [&](float* v, int k0) {
        const int kk = k0 + w * 8;                  // wave-uniform
        if (kk >= CONCAT && kk + 8 <= Kvalid) {
            const float* p = A2p + grow * COND_D + (kk - CONCAT);
            *(float4*)&v[0] = *(const float4*)p;
            *(float4*)&v[4] = *(const float4*)(p + 4);
        } else if (kk + 8 <= CONCAT) {
            const float* p = A1p + grow * CONCAT + kk;
            *(float4*)&v[0] = *(const float4*)p;
            *(float4*)&v[4] = *(const float4*)(p + 4);
        } else {
#pragma unroll
            for (int i = 0; i < 8; ++i) {
                int k = kk + i;
                v[i] = (k < CONCAT) ? A1p[grow * CONCAT + k]
                     : (k < Kvalid) ? A2p[grow * COND_D + (k - CONCAT)] : 0.0f;
            }
        }
    };
    auto awrite = [&](int buf, const float* v) {
        uint hh[4], ll[4];
#pragma unroll
        for (int i = 0; i < 4; ++i) {
            ushort_t h0, l0, h1, l1;
            splitf(v[2 * i], h0, l0);
            splitf(v[2 * i + 1], h1, l1);
            hh[i] = (uint)h0 | ((uint)h1 << 16);
            ll[i] = (uint)l0 | ((uint)l1 << 16);
        }
        *(uint4*)&lds[buf * 2048 + w * 256 + l * 4]        = *(uint4*)hh;
        *(uint4*)&lds[buf * 2048 + 1024 + w * 256 + l * 4] = *(uint4*)ll;
    };

    // ---- compute: A from LDS, B from current regs ----
    auto compute = [&](int buf) {
        const int base = buf * 2048;
        half8 bh0 = __builtin_bit_cast(half8, bch0);
        half8 bh1 = __builtin_bit_cast(half8, bch1);
        half8 bl0 = __builtin_bit_cast(half8, bcl0);
        half8 bl1 = __builtin_bit_cast(half8, bcl1);
#pragma unroll
        for (int im = 0; im < 4; ++im) {
            int aoff = base + quad * 256 + (im * 16 + lr) * 4;
            half8 ah = __builtin_bit_cast(half8, *(uint4*)&lds[aoff]);
            half8 al = __builtin_bit_cast(half8, *(uint4*)&lds[aoff + 1024]);
            accH[im][0] = __builtin_amdgcn_mfma_f32_16x16x32_f16(ah, bh0, accH[im][0], 0, 0, 0);
            accX[im][0] = __builtin_amdgcn_mfma_f32_16x16x32_f16(ah, bl0, accX[im][0], 0, 0, 0);
            accX[im][0] = __builtin_amdgcn_mfma_f32_16x16x32_f16(al, bh0, accX[im][0], 0, 0, 0);
            accH[im][1] = __builtin_amdgcn_mfma_f32_16x16x32_f16(ah, bh1, accH[im][1], 0, 0, 0);
            accX[im][1] = __builtin_amdgcn_mfma_f32_16x16x32_f16(ah, bl1, accX[im][1], 0, 0, 0);
            accX[im][1] = __builtin_amdgcn_mfma_f32_16x16x32_f16(al, bh1, accX[im][1], 0, 0, 0);
        }
    };

    const int kTiles = Kp / 32;
    int cur = 0;
    float v[8];

    // ---- prologue: tile 0 -> buffer 0 / current B regs ----
    if constexpr (CONCAT == 0) {
        stageA0(0, 0);                      // A0 DMA
        loadBcur(0);                        // B0 regs
        __syncthreads();                    // drains DMA + publishes buf0
    } else {
        aload(v, 0);
        loadBcur(0);
        awrite(0, v);                       // compiler waits for aload regs
        __syncthreads();                    // publishes buf0 A
    }

    // ---- main loop ----
    for (int t = 0; t < kTiles; ++t) {
        const bool hasNext = (t + 1 < kTiles);
        const int k0n = (t + 1) * 32;
        if constexpr (CONCAT == 0 && BDBUF) {
            // v7 schedule (reg-lean instantiation): everything before compute
            if (hasNext) {
                stageA0(cur ^ 1, k0n);      // A[t+1] DMA in flight during compute
                loadBnext(k0n);             // B[t+1] -> separate regs, in flight
            }
            compute(cur);                   // no waits: cur A (LDS) + cur B regs
        } else if constexpr (CONCAT == 0) {
            // v5 schedule (verbatim)
            if (hasNext) stageA0(cur ^ 1, k0n);
            compute(cur);
            if (hasNext) loadBcur(k0n);     // after last B-cur use
        } else {
            // v5 CONCAT schedule (verbatim)
            if (hasNext) aload(v, k0n);     // A[t+1] fp32 -> regs (issue early)
            compute(cur);
            if (hasNext) {
                awrite(cur ^ 1, v);         // convert + ds_write A[t+1]
                loadBcur(k0n);              // B[t+1]
            }
        }
        __syncthreads();                    // drain + publish; buf swap safe
        if constexpr (CONCAT == 0 && BDBUF) { if (hasNext) promoteB(); }
        cur ^= 1;
    }

    // ---- epilogue: combine, bias, ELU, hi/lo split store ----
    float bv[2];
#pragma unroll
    for (int jn = 0; jn < 2; ++jn) bv[jn] = bias[colBase + nQ + jn * 16 + lr];
#pragma unroll
    for (int im = 0; im < 4; ++im) {
#pragma unroll
        for (int jn = 0; jn < 2; ++jn) {
            int n = colBase + nQ + jn * 16 + lr;
#pragma unroll
            for (int rr = 0; rr < 4; ++rr) {
                long m = rowBase + im * 16 + quad * 4 + rr;
                float x = accH[im][jn][rr] + accX[im][jn][rr] * INV_LO_SCALE + bv[jn];
                x = x > 0.0f ? x : (expf(x) - 1.0f);
                ushort_t h, lo; splitf(x, h, lo);
                long idx = m * Nw + n;
                Chi[idx] = h;
                Clo[idx] = lo;
            }
        }
    }
}

// ---------------------------------------------------------------------------
// K3: z = h2@W3+b3 (fp32, h2 = hi + lo*2^-12), normalize, argmax,
// quantized -> d_out, q-latent partial, counts, distT (transposed) write.
// ---------------------------------------------------------------------------
__global__ __launch_bounds__(256)
void quantize_kernel(const ushort_t* __restrict__ h2hi, const ushort_t* __restrict__ h2lo,
                     const float* __restrict__ W3,
                     const float* __restrict__ b3, const float* __restrict__ emb,
                     float* __restrict__ distT, float* __restrict__ outQ,
                     float* __restrict__ outIdx, int* __restrict__ counts,
                     float* __restrict__ qsum)
{
    __shared__ float h2t[16 * 260];
    __shared__ float w3t[16 * 260];
    __shared__ float nwt[256 * 20];
    __shared__ float zt[16 * 17];
    __shared__ float dt[16 * 257];
    __shared__ int   lcnt[256];
    __shared__ float swred[4];

    int t = threadIdx.x;
    long rowBase = (long)blockIdx.x * 16;

    for (int it = 0; it < 16; ++it) {
        long idx = (rowBase + it) * 256 + t;
        h2t[it * 260 + t] = f16pair(h2hi[idx], h2lo[idx]);
    }
    for (int it = 0; it < 16; ++it) {
        int flat = it * 256 + t;
        int j = flat >> 4, c = flat & 15;
        w3t[c * 260 + j] = W3[flat];
    }
    {
        float e0[16]; float ss = 0.f;
#pragma unroll
        for (int i = 0; i < 16; ++i) { e0[i] = emb[t * 16 + i]; ss += e0[i] * e0[i]; }
        float inv = 1.0f / fmaxf(sqrtf(ss), 1e-12f);
#pragma unroll
        for (int i = 0; i < 16; ++i) nwt[t * 20 + i] = e0[i] * inv;
    }
    lcnt[t] = 0;
    __syncthreads();

    int r = t >> 4, c = t & 15;
    float zacc = b3[c];
    for (int j4 = 0; j4 < 64; ++j4) {
        float4 h = *(const float4*)&h2t[r * 260 + j4 * 4];
        float4 w = *(const float4*)&w3t[c * 260 + j4 * 4];
        zacc += h.x * w.x + h.y * w.y + h.z * w.z + h.w * w.w;
    }
    float ss = zacc * zacc;
#pragma unroll
    for (int m = 1; m < 16; m <<= 1) ss += __shfl_xor(ss, m, 64);
    zt[r * 17 + c] = zacc / fmaxf(sqrtf(ss), 1e-12f);
    __syncthreads();

    float zr[16];
#pragma unroll
    for (int e = 0; e < 16; ++e) zr[e] = zt[r * 17 + e];
    float best = -1e30f; int bidx = 0;
    for (int cc = 0; cc < 16; ++cc) {
        int col = cc * 16 + c;
        float d = 0.f;
#pragma unroll
        for (int e4 = 0; e4 < 4; ++e4) {
            float4 wv = *(const float4*)&nwt[col * 20 + e4 * 4];
            d += zr[e4 * 4 + 0] * wv.x + zr[e4 * 4 + 1] * wv.y
               + zr[e4 * 4 + 2] * wv.z + zr[e4 * 4 + 3] * wv.w;
        }
        dt[r * 257 + col] = d;
        if (d > best || (d == best && col < bidx)) { best = d; bidx = col; }
    }
#pragma unroll
    for (int m = 1; m < 16; m <<= 1) {
        float ov = __shfl_xor(best, m, 64);
        int   oi = __shfl_xor(bidx, m, 64);
        if (ov > best || (ov == best && oi < bidx)) { best = ov; bidx = oi; }
    }

    float q = emb[bidx * 16 + c];
    outQ[(rowBase + r) * 16 + c] = q;
    float df = q - zacc;
    float part = df * df;
#pragma unroll
    for (int m = 1; m < 64; m <<= 1) part += __shfl_xor(part, m, 64);
    if ((t & 63) == 0) swred[t >> 6] = part;
    if (c == 0) {
        outIdx[rowBase + r] = (float)bidx;
        atomicAdd(&lcnt[bidx], 1);
    }
    __syncthreads();
    if (t == 0) atomicAdd(qsum, swred[0] + swred[1] + swred[2] + swred[3]);
    if (lcnt[t] > 0) atomicAdd(&counts[t], lcnt[t]);

    int rr = t & 15, cg = t >> 4;
    for (int i = 0; i < 16; ++i) {
        int col = i * 16 + cg;
        distT[(long)col * NROWS + rowBase + rr] = dt[rr * 257 + col];
    }
}

// ---------------------------------------------------------------------------
// SelA: per-column histogram; median bin and top-512 threshold bin.
// ---------------------------------------------------------------------------
__global__ __launch_bounds__(1024)
void selA_kernel(const float* __restrict__ distT, int* __restrict__ stats)
{
    __shared__ int hist[NB];
    __shared__ int part[1024];
    int t = threadIdx.x, c = blockIdx.x;
    for (int i = t; i < NB; i += 1024) hist[i] = 0;
    __syncthreads();
    const float* col = distT + (long)c * NROWS;
    for (int i = t; i < NROWS; i += 1024) {
        float v = col[i];
        int b = (int)((v + 1.0f) * (NB * 0.5f));
        b = min(max(b, 0), NB - 1);
        atomicAdd(&hist[b], 1);
    }
    __syncthreads();
    const int CH = NB / 1024;
    int s = 0;
    for (int i = 0; i < CH; ++i) s += hist[t * CH + i];
    part[t] = s;
    __syncthreads();
    if (t == 0) {
        int target = NROWS / 2;
        int cum = 0; int chunk = 0;
        while (cum + part[chunk] < target) { cum += part[chunk]; ++chunk; }
        int b = chunk * CH;
        while (cum + hist[b] < target) { cum += hist[b]; ++b; }
        int medBin = b, needLow = target - cum, cntMed = hist[b];
        int cumA = 0; chunk = 1023;
        while (cumA + part[chunk] < 512) { cumA += part[chunk]; --chunk; }
        b = chunk * CH + CH - 1;
        while (cumA + hist[b] < 512) { cumA += hist[b]; --b; }
        int topBin = b, needTop = 512 - cumA, cntTop = hist[b];
        int* st = stats + c * 6;
        st[0] = medBin; st[1] = needLow; st[2] = cntMed;
        st[3] = topBin; st[4] = needTop; st[5] = cntTop;
    }
}

// ---------------------------------------------------------------------------
// SelB: re-scan column; top-512 mean and logsumexp over bottom half.
// ---------------------------------------------------------------------------
__global__ __launch_bounds__(1024)
void selB_kernel(const float* __restrict__ distT, const int* __restrict__ stats,
                 float* __restrict__ contra_sum)
{
    __shared__ float red[64];
    int t = threadIdx.x, c = blockIdx.x;
    const int* st = stats + c * 6;
    int medBin = st[0], needLow = st[1], cntMed = st[2];
    int topBin = st[3], needTop = st[4], cntTop = st[5];
    const float binw = 2.0f / NB;
    float mUp = -1.0f + (medBin + 1) * binw;
    const float INVT = 1.0f / 0.07f;
    const float* col = distT + (long)c * NROWS;
    float topS = 0.f, tbS = 0.f, lowS = 0.f, mbS = 0.f;
    for (int i = t; i < NROWS; i += 1024) {
        float v = col[i];
        int b = (int)((v + 1.0f) * (NB * 0.5f));
        b = min(max(b, 0), NB - 1);
        if (b > topBin)       topS += v;
        else if (b == topBin) tbS += v;
        if (b < medBin)       lowS += expf((v - mUp) * INVT);
        else if (b == medBin) mbS  += expf((v - mUp) * INVT);
    }
#pragma unroll
    for (int m = 1; m < 64; m <<= 1) {
        topS += __shfl_xor(topS, m, 64);
        tbS  += __shfl_xor(tbS, m, 64);
        lowS += __shfl_xor(lowS, m, 64);
        mbS  += __shfl_xor(mbS, m, 64);
    }
    if ((t & 63) == 0) {
        int wv = t >> 6;
        red[wv * 4 + 0] = topS; red[wv * 4 + 1] = tbS;
        red[wv * 4 + 2] = lowS; red[wv * 4 + 3] = mbS;
    }
    __syncthreads();
    if (t == 0) {
        float T0 = 0, T1 = 0, T2 = 0, T3 = 0;
        for (int wv = 0; wv < 16; ++wv) {
            T0 += red[wv * 4 + 0]; T1 += red[wv * 4 + 1];
            T2 += red[wv * 4 + 2]; T3 += red[wv * 4 + 3];
        }
        float dis_pos = (T0 + needTop * (T1 / cntTop)) * (1.0f / 512.0f);
        float S = T2 + needLow * (T3 / cntMed);
        float colContra = log1pf(S * expf((mUp - dis_pos) * INVT));
        atomicAdd(contra_sum, colContra);
    }
}

// ---------------------------------------------------------------------------
// D3: reconstructed = d2 @ dec_w3 + b (d2 = hi + lo*2^-12), + recon loss.
// ---------------------------------------------------------------------------
__global__ __launch_bounds__(256)
void dec3_kernel(const ushort_t* __restrict__ d2hi, const ushort_t* __restrict__ d2lo,
                 const float* __restrict__ W,
                 const float* __restrict__ bias, const float* __restrict__ actions,
                 float* __restrict__ rec, float* __restrict__ recon_sum)
{
    __shared__ float dtile[16 * 516];
    __shared__ float wt[512 * 12];
    __shared__ float red2[4];
    int t = threadIdx.x;
    long rowBase = (long)blockIdx.x * 16;
    for (int it = 0; it < 24; ++it) wt[it * 256 + t] = W[it * 256 + t];
    for (int it = 0; it < 32; ++it) {
        int flat = it * 256 + t;
        int r = flat >> 9, k = flat & 511;
        long idx = (rowBase + r) * 512 + k;
        dtile[r * 516 + k] = f16pair(d2hi[idx], d2lo[idx]);
    }
    __syncthreads();
    float part = 0.f;
    if (t < 192) {
        int r = t / 12, cc = t % 12;
        float acc = bias[cc];
        for (int k4 = 0; k4 < 128; ++k4) {
            float4 h = *(const float4*)&dtile[r * 516 + k4 * 4];
            acc += h.x * wt[(k4 * 4 + 0) * 12 + cc] + h.y * wt[(k4 * 4 + 1) * 12 + cc]
                 + h.z * wt[(k4 * 4 + 2) * 12 + cc] + h.w * wt[(k4 * 4 + 3) * 12 + cc];
        }
        rec[(rowBase + r) * 12 + cc] = acc;
        float df = acc - actions[(rowBase + r) * 12 + cc];
        part = df * df;
    }
#pragma unroll
    for (int m = 1; m < 64; m <<= 1) part += __shfl_xor(part, m, 64);
    if ((t & 63) == 0) red2[t >> 6] = part;
    __syncthreads();
    if (t == 0) atomicAdd(recon_sum, red2[0] + red2[1] + red2[2] + red2[3]);
}

// ---------------------------------------------------------------------------
// finalize: perplexity from counts + scalar outputs.
// ---------------------------------------------------------------------------
__global__ void finalize_kernel(const int* __restrict__ counts, float* __restrict__ outScal)
{
    __shared__ float red[4];
    int t = threadIdx.x;
    float p = counts[t] * (1.0f / NROWS);
    float term = p * logf(p + 1e-10f);
#pragma unroll
    for (int m = 1; m < 64; m <<= 1) term += __shfl_xor(term, m, 64);
    if ((t & 63) == 0) red[t >> 6] = term;
    __syncthreads();
    if (t == 0) {
        float hsum = red[0] + red[1] + red[2] + red[3];
        float qsum = outScal[0], contra = outScal[2], recon = outScal[4];
        float ql = qsum * (1.0f / (NROWS * 16.0f));
        outScal[0] = ql;
        outScal[1] = 0.25f * ql;
        outScal[2] = contra * (1.0f / 256.0f);
        outScal[3] = expf(-hsum);
        outScal[4] = recon * (1.0f / (NROWS * 12.0f));
    }
}

extern "C" void kernel_launch(void* const* d_in, const int* in_sizes, int n_in,
                              void* d_out, int out_size, void* d_ws, size_t ws_size,
                              hipStream_t stream)
{
    const float* actions    = (const float*)d_in[0];
    const float* conditions = (const float*)d_in[1];
    const float* enc_w1 = (const float*)d_in[2];
    const float* enc_b1 = (const float*)d_in[3];
    const float* enc_w2 = (const float*)d_in[4];
    const float* enc_b2 = (const float*)d_in[5];
    const float* enc_w3 = (const float*)d_in[6];
    const float* enc_b3 = (const float*)d_in[7];
    const float* dec_w1 = (const float*)d_in[8];
    const float* dec_b1 = (const float*)d_in[9];
    const float* dec_w2 = (const float*)d_in[10];
    const float* dec_b2 = (const float*)d_in[11];
    const float* dec_w3 = (const float*)d_in[12];
    const float* dec_b3 = (const float*)d_in[13];
    const float* emb    = (const float*)d_in[14];

    float* out     = (float*)d_out;
    float* outRec  = out;
    float* outQ    = out + (long)NROWS * 12;
    float* outIdx  = out + (long)NROWS * 28;
    float* outScal = out + (long)NROWS * 29;

    // converted weights live in the (dead-until-dec3) outRec region
    ushort_t* wb    = (ushort_t*)d_out;
    ushort_t* w1hi  = wb;            ushort_t* w1lo  = wb + 147456;
    ushort_t* w2hi  = wb + 294912;   ushort_t* w2lo  = wb + 425984;
    ushort_t* wd1hi = wb + 557056;   ushort_t* wd1lo = wb + 630784;
    ushort_t* wd2hi = wb + 704512;   ushort_t* wd2lo = wb + 835584;

    float* ws = (float*)d_ws;
    int* counts = (int*)ws;
    int* stats  = (int*)(ws + 256);
    ushort_t* h2hi = (ushort_t*)(ws + 1792);
    ushort_t* h2lo = (ushort_t*)(ws + 16779008);
    ushort_t* d1hi = h2hi;
    ushort_t* d1lo = h2lo;
    float*    P1   = ws + 33556224;
    ushort_t* h1hi = (ushort_t*)P1;
    ushort_t* h1lo = (ushort_t*)(ws + 67110656);
    float*    distT = P1;
    ushort_t* d2hi = h1hi;
    ushort_t* d2lo = h1lo;

    hipLaunchKernelGGL(init_kernel, dim3(1), dim3(256), 0, stream, counts, outScal);
    hipLaunchKernelGGL(convw_kernel, dim3(512, 2), dim3(256), 0, stream, enc_w1, w1hi, w1lo, 268, 512, 288);
    hipLaunchKernelGGL(convw_kernel, dim3(256, 2), dim3(256), 0, stream, enc_w2, w2hi, w2lo, 512, 256, 512);
    hipLaunchKernelGGL(convw_kernel, dim3(256, 2), dim3(256), 0, stream, dec_w1, wd1hi, wd1lo, 272, 256, 288);
    hipLaunchKernelGGL(convw_kernel, dim3(512, 1), dim3(256), 0, stream, dec_w2, wd2hi, wd2lo, 256, 512, 256);
    // E1: h1 = elu(concat(actions,conditions) @ W1 + b1)  [v5 schedule]
    hipLaunchKernelGGL((gemm_f16x3_kernel<ACT_D, 0>), dim3(2048, 4), dim3(256), 0, stream,
                       (const void*)actions, (const void*)conditions, w1hi, w1lo, enc_b1,
                       h1hi, h1lo, H1D, 288, 268);
    // E2: h2 = elu(h1 @ W2 + b2)  [B-dbuf schedule]
    hipLaunchKernelGGL((gemm_f16x3_kernel<0, 1>), dim3(2048, 2), dim3(256), 0, stream,
                       (const void*)h1hi, (const void*)h1lo, w2hi, w2lo, enc_b2,
                       h2hi, h2lo, H2D, 512, 512);
    // K3: z, normalize, argmax, quantized, counts, q-latent, distT
    hipLaunchKernelGGL(quantize_kernel, dim3(8192), dim3(256), 0, stream,
                       h2hi, h2lo, enc_w3, enc_b3, emb, distT, outQ, outIdx, counts, &outScal[0]);
    hipLaunchKernelGGL(selA_kernel, dim3(256), dim3(1024), 0, stream, distT, stats);
    hipLaunchKernelGGL(selB_kernel, dim3(256), dim3(1024), 0, stream, distT, stats, &outScal[2]);
    // D1: d1 = elu(concat(quantized,conditions) @ Wd1 + b1)  [v5 schedule]
    hipLaunchKernelGGL((gemm_f16x3_kernel<EDIM, 0>), dim3(2048, 2), dim3(256), 0, stream,
                       (const void*)outQ, (const void*)conditions, wd1hi, wd1lo, dec_b1,
                       d1hi, d1lo, H2D, 288, 272);
    // D2: d2 = elu(d1 @ Wd2 + b2)  [B-dbuf schedule]
    hipLaunchKernelGGL((gemm_f16x3_kernel<0, 1>), dim3(2048, 4), dim3(256), 0, stream,
                       (const void*)d1hi, (const void*)d1lo, wd2hi, wd2lo, dec_b2,
                       d2hi, d2lo, H1D, 256, 256);
    // D3: reconstructed + loss
    hipLaunchKernelGGL(dec3_kernel, dim3(8192), dim3(256), 0, stream,
                       d2hi, d2lo, dec_w3, dec_b3, actions, outRec, &outScal[4]);
    hipLaunchKernelGGL(finalize_kernel, dim3(1), dim3(256), 0, stream, counts, outScal);
}

// Round 10
// 1466.439 us; speedup vs baseline: 1.2206x; 1.0092x over previous
//
#include <hip/hip_runtime.h>
#include <hip/hip_bf16.h>
#include <math.h>

#define NROWS 131072
#define ACT_D 12
#define COND_D 256
#define KEMB 256
#define EDIM 16
#define H1D 512
#define H2D 256
#define NB 16384

typedef __attribute__((ext_vector_type(8))) _Float16 half8;
typedef __attribute__((ext_vector_type(4))) float floatx4;
typedef unsigned short ushort_t;

#define LO_SCALE 4096.0f
#define INV_LO_SCALE 2.44140625e-4f

// ---------------------------------------------------------------------------
// Memory plan (unchanged).
// d_ws:
//   counts @ 0        (256 ints)
//   stats  @ 256      (1536 ints)
//   P2     @ 1792     : h2hi/h2lo -> d1hi/d1lo (f16 pairs)
//   P1     @ 33556224 : h1hi/h1lo -> distT(fp32) -> d2hi/d2lo
// d_out outRec region hosts converted transposed hi/lo-split weights until D2.
//
// Numerics: fp32 a = hi + lo*2^-12, hi=f16(a), lo=f16((a-hi)*4096).
// A@B = AhiBhi (accH) + (AhiBlo'+Alo'Bhi) (accX), out = accH + accX*2^-12.
//
// GEMM v10 = v5 + BK=64 rounds for CONCAT==0 (E2/D2). R9 measured: both
// pipes >=80% idle (MfmaUtil 16, VALU 17, LDS-port ~14%, HBM 19%) -> the
// per-step barrier round's FIXED cost (~450 of 750 eff cycles) is the
// plateau; R8 confirmed from the other side (half work/step -> worse).
// Fix: two K-sub-tiles per barrier round (48 MFMA/wave/round): stage 4
// A-DMAs (next round) before compute, compute sub0, reload B (sub1, same
// regs - v5's measured pattern), compute sub1, ONE barrier. LDS 32KB x 4
// blocks = 128KB <= 160; regs unchanged -> 4 waves/SIMD kept. E1/D1
// (CONCAT!=0, K=288 not 64-divisible) keep the R5-verified BK=32 schedule
// verbatim. K-tile order identical -> bitwise-same outputs.
// ---------------------------------------------------------------------------

__global__ void init_kernel(int* counts, float* outScal) {
    int t = threadIdx.x;
    counts[t] = 0;
    if (t < 5) outScal[t] = 0.0f;
}

__device__ inline ushort_t f16bits(_Float16 h) { return __builtin_bit_cast(ushort_t, h); }
__device__ inline float f16pair(ushort_t a, ushort_t b) {
    return (float)__builtin_bit_cast(_Float16, a)
         + (float)__builtin_bit_cast(_Float16, b) * INV_LO_SCALE;
}
__device__ inline void splitf(float v, ushort_t& hi, ushort_t& lo) {
    _Float16 h = (_Float16)v;
    _Float16 l = (_Float16)((v - (float)h) * LO_SCALE);
    hi = f16bits(h); lo = f16bits(l);
}

__device__ inline void gload_lds16(const void* g, void* lds) {
    __builtin_amdgcn_global_load_lds((const __attribute__((address_space(1))) void*)g,
                                     (__attribute__((address_space(3))) void*)lds, 16, 0, 0);
}

// ---------------------------------------------------------------------------
// Weight conversion: W [K,N] fp32 -> Whi/Wlo [N,Kp] f16 (transposed, padded).
// ---------------------------------------------------------------------------
__global__ __launch_bounds__(256)
void convw_kernel(const float* __restrict__ W, ushort_t* __restrict__ Whi,
                  ushort_t* __restrict__ Wlo, int K, int N, int Kp)
{
    int n = blockIdx.x;
    int k = blockIdx.y * 256 + threadIdx.x;
    if (k >= Kp) return;
    float v = (k < K) ? W[(long)k * N + n] : 0.0f;
    ushort_t h, l; splitf(v, h, l);
    Whi[(long)n * Kp + k] = h;
    Wlo[(long)n * Kp + k] = l;
}

// ---------------------------------------------------------------------------
// f16x3 (scaled-lo) MFMA GEMM + bias + ELU.  C = elu(A @ W + b).
// BM=64, BN=128, 256 thr (4 waves; wave w owns rows 0..63 x cols
// [w*32, w*32+32)).  A: LDS double-buffer via DMA (or reg-staged concat).
// B: direct per-lane global_load_dwordx4 from L2.
// CONCAT==0: BK=64 rounds. LDS (uints), per buffer 4096:
//   sub-tile s at s*2048: Ahi [0,1024) (k-quad q at q*256+row*4), Alo [+1024)
// CONCAT!=0: BK=32 (v5 verbatim), buffer stride 2048.
// MFMA mappings (m89/m120-verified): A[m=lane&15][k=quad*8+j],
// B[k=quad*8+j][n=lane&15], C col=lane&15 row=quad*4+reg.
// ---------------------------------------------------------------------------
template<int CONCAT>
__global__ __launch_bounds__(256, 3)
void gemm_f16x3_kernel(const void* A0v, const void* A1v,
                       const ushort_t* __restrict__ Bhi, const ushort_t* __restrict__ Blo,
                       const float* __restrict__ bias,
                       ushort_t* __restrict__ Chi, ushort_t* __restrict__ Clo,
                       int Nw, int Kp, int Kvalid)
{
    constexpr int LDSW = (CONCAT == 0) ? 8192 : 4096;
    __shared__ uint lds[LDSW];
    const int tid = threadIdx.x;
    const int w = tid >> 6, l = tid & 63;
    const int quad = l >> 4, lr = l & 15;
    const long rowBase = (long)blockIdx.x * 64;
    const int colBase = blockIdx.y * 128;
    const int nQ = w * 32;

    floatx4 accH[4][2], accX[4][2];
#pragma unroll
    for (int i = 0; i < 4; ++i)
#pragma unroll
        for (int j = 0; j < 2; ++j) { accH[i][j] = (floatx4)(0.0f); accX[i][j] = (floatx4)(0.0f); }

    // ---- B fragment offsets (32-bit voffset form; SGPR base + v_off) ----
    const uint off0 = (uint)((colBase + nQ + lr) * Kp + quad * 8);
    const uint off1 = off0 + (uint)(16 * Kp);

    uint4 bch0, bch1, bcl0, bcl1;                   // current B fragments (named)
    auto loadB = [&](int k0) {
        bch0 = *(const uint4*)(Bhi + off0 + k0);
        bch1 = *(const uint4*)(Bhi + off1 + k0);
        bcl0 = *(const uint4*)(Blo + off0 + k0);
        bcl1 = *(const uint4*)(Blo + off1 + k0);
    };

    // ---- A staging, DMA path (CONCAT==0): A already f16 hi/lo, [M,Kp].
    // Stages a full 64-wide K round (2 sub-tiles) into buffer buf.
    const ushort_t* pAh = (const ushort_t*)A0v + (rowBase + l) * Kp + w * 8;
    const ushort_t* pAl = (const ushort_t*)A1v + (rowBase + l) * Kp + w * 8;
    auto stageA64 = [&](int buf, int k0) {
        uint* d = &lds[buf * 4096 + w * 256];
        gload_lds16(pAh + k0, d);                   // sub0 hi
        gload_lds16(pAl + k0, d + 1024);            // sub0 lo
        gload_lds16(pAh + k0 + 32, d + 2048);       // sub1 hi
        gload_lds16(pAl + k0 + 32, d + 3072);       // sub1 lo
    };

    // ---- A staging, fp32-concat path (CONCAT!=0): load->regs, convert,
    //      ds_write (all compiler-scoreboarded; __syncthreads publishes). ----
    const float* A1p = (const float*)A0v;
    const float* A2p = (const float*)A1v;
    const long grow = rowBase + l;

    auto aload = [&](float* v, int k0) {
        const int kk = k0 + w * 8;                  // wave-uniform
        if (kk >= CONCAT && kk + 8 <= Kvalid) {
            const float* p = A2p + grow * COND_D + (kk - CONCAT);
            *(float4*)&v[0] = *(const float4*)p;
            *(float4*)&v[4] = *(const float4*)(p + 4);
        } else if (kk + 8 <= CONCAT) {
            const float* p = A1p + grow * CONCAT + kk;
            *(float4*)&v[0] = *(const float4*)p;
            *(float4*)&v[4] = *(const float4*)(p + 4);
        } else {
#pragma unroll
            for (int i = 0; i < 8; ++i) {
                int k = kk + i;
                v[i] = (k < CONCAT) ? A1p[grow * CONCAT + k]
                     : (k < Kvalid) ? A2p[grow * COND_D + (k - CONCAT)] : 0.0f;
            }
        }
    };
    auto awrite = [&](int buf, const float* v) {
        uint hh[4], ll[4];
#pragma unroll
        for (int i = 0; i < 4; ++i) {
            ushort_t h0, l0, h1, l1;
            splitf(v[2 * i], h0, l0);
            splitf(v[2 * i + 1], h1, l1);
            hh[i] = (uint)h0 | ((uint)h1 << 16);
            ll[i] = (uint)l0 | ((uint)l1 << 16);
        }
        *(uint4*)&lds[buf * 2048 + w * 256 + l * 4]        = *(uint4*)hh;
        *(uint4*)&lds[buf * 2048 + 1024 + w * 256 + l * 4] = *(uint4*)ll;
    };

    // ---- compute: A sub-tile at LDS uint index `base`, B from regs ----
    auto compute = [&](int base) {
        half8 bh0 = __builtin_bit_cast(half8, bch0);
        half8 bh1 = __builtin_bit_cast(half8, bch1);
        half8 bl0 = __builtin_bit_cast(half8, bcl0);
        half8 bl1 = __builtin_bit_cast(half8, bcl1);
#pragma unroll
        for (int im = 0; im < 4; ++im) {
            int aoff = base + quad * 256 + (im * 16 + lr) * 4;
            half8 ah = __builtin_bit_cast(half8, *(uint4*)&lds[aoff]);
            half8 al = __builtin_bit_cast(half8, *(uint4*)&lds[aoff + 1024]);
            accH[im][0] = __builtin_amdgcn_mfma_f32_16x16x32_f16(ah, bh0, accH[im][0], 0, 0, 0);
            accX[im][0] = __builtin_amdgcn_mfma_f32_16x16x32_f16(ah, bl0, accX[im][0], 0, 0, 0);
            accX[im][0] = __builtin_amdgcn_mfma_f32_16x16x32_f16(al, bh0, accX[im][0], 0, 0, 0);
            accH[im][1] = __builtin_amdgcn_mfma_f32_16x16x32_f16(ah, bh1, accH[im][1], 0, 0, 0);
            accX[im][1] = __builtin_amdgcn_mfma_f32_16x16x32_f16(ah, bl1, accX[im][1], 0, 0, 0);
            accX[im][1] = __builtin_amdgcn_mfma_f32_16x16x32_f16(al, bh1, accX[im][1], 0, 0, 0);
        }
    };

    if constexpr (CONCAT == 0) {
        // ---- BK=64 rounds: 2 sub-tiles per barrier (Kp % 64 == 0) ----
        const int nR = Kp / 64;
        int buf = 0;
        stageA64(0, 0);                     // round 0 A (2 sub-tiles)
        loadB(0);                           // B sub0
        __syncthreads();                    // drains DMA + publishes buf0
        for (int r = 0; r < nR; ++r) {
            const bool hasNext = (r + 1 < nR);
            if (hasNext) stageA64(buf ^ 1, (r + 1) * 64);  // next round A in flight
            compute(buf * 4096);            // sub0 (B already resident)
            loadB(r * 64 + 32);             // B sub1 (reuse regs after last use)
            compute(buf * 4096 + 2048);     // sub1
            if (hasNext) loadB((r + 1) * 64);  // B for next round's sub0
            __syncthreads();                // one drain per 64-wide round
            buf ^= 1;
        }
    } else {
        // ---- v5 BK=32 concat schedule (verbatim; buffer stride 2048) ----
        const int kTiles = Kp / 32;
        int cur = 0;
        float v[8];
        aload(v, 0);
        loadB(0);
        awrite(0, v);                       // compiler waits for aload regs
        __syncthreads();                    // publishes buf0 A
        for (int t = 0; t < kTiles; ++t) {
            const bool hasNext = (t + 1 < kTiles);
            const int k0n = (t + 1) * 32;
            if (hasNext) aload(v, k0n);     // A[t+1] fp32 -> regs (issue early)
            compute(cur * 2048);
            if (hasNext) {
                awrite(cur ^ 1, v);         // convert + ds_write A[t+1]
                loadB(k0n);                 // B[t+1]
            }
            __syncthreads();                // drain + publish; buf swap safe
            cur ^= 1;
        }
    }

    // ---- epilogue: combine, bias, ELU, hi/lo split store ----
    float bv[2];
#pragma unroll
    for (int jn = 0; jn < 2; ++jn) bv[jn] = bias[colBase + nQ + jn * 16 + lr];
#pragma unroll
    for (int im = 0; im < 4; ++im) {
#pragma unroll
        for (int jn = 0; jn < 2; ++jn) {
            int n = colBase + nQ + jn * 16 + lr;
#pragma unroll
            for (int rr = 0; rr < 4; ++rr) {
                long m = rowBase + im * 16 + quad * 4 + rr;
                float x = accH[im][jn][rr] + accX[im][jn][rr] * INV_LO_SCALE + bv[jn];
                x = x > 0.0f ? x : (expf(x) - 1.0f);
                ushort_t h, lo; splitf(x, h, lo);
                long idx = m * Nw + n;
                Chi[idx] = h;
                Clo[idx] = lo;
            }
        }
    }
}

// ---------------------------------------------------------------------------
// K3: z = h2@W3+b3 (fp32, h2 = hi + lo*2^-12), normalize, argmax,
// quantized -> d_out, q-latent partial, counts, distT (transposed) write.
// ---------------------------------------------------------------------------
__global__ __launch_bounds__(256)
void quantize_kernel(const ushort_t* __restrict__ h2hi, const ushort_t* __restrict__ h2lo,
                     const float* __restrict__ W3,
                     const float* __restrict__ b3, const float* __restrict__ emb,
                     float* __restrict__ distT, float* __restrict__ outQ,
                     float* __restrict__ outIdx, int* __restrict__ counts,
                     float* __restrict__ qsum)
{
    __shared__ float h2t[16 * 260];
    __shared__ float w3t[16 * 260];
    __shared__ float nwt[256 * 20];
    __shared__ float zt[16 * 17];
    __shared__ float dt[16 * 257];
    __shared__ int   lcnt[256];
    __shared__ float swred[4];

    int t = threadIdx.x;
    long rowBase = (long)blockIdx.x * 16;

    for (int it = 0; it < 16; ++it) {
        long idx = (rowBase + it) * 256 + t;
        h2t[it * 260 + t] = f16pair(h2hi[idx], h2lo[idx]);
    }
    for (int it = 0; it < 16; ++it) {
        int flat = it * 256 + t;
        int j = flat >> 4, c = flat & 15;
        w3t[c * 260 + j] = W3[flat];
    }
    {
        float e0[16]; float ss = 0.f;
#pragma unroll
        for (int i = 0; i < 16; ++i) { e0[i] = emb[t * 16 + i]; ss += e0[i] * e0[i]; }
        float inv = 1.0f / fmaxf(sqrtf(ss), 1e-12f);
#pragma unroll
        for (int i = 0; i < 16; ++i) nwt[t * 20 + i] = e0[i] * inv;
    }
    lcnt[t] = 0;
    __syncthreads();

    int r = t >> 4, c = t & 15;
    float zacc = b3[c];
    for (int j4 = 0; j4 < 64; ++j4) {
        float4 h = *(const float4*)&h2t[r * 260 + j4 * 4];
        float4 w = *(const float4*)&w3t[c * 260 + j4 * 4];
        zacc += h.x * w.x + h.y * w.y + h.z * w.z + h.w * w.w;
    }
    float ss = zacc * zacc;
#pragma unroll
    for (int m = 1; m < 16; m <<= 1) ss += __shfl_xor(ss, m, 64);
    zt[r * 17 + c] = zacc / fmaxf(sqrtf(ss), 1e-12f);
    __syncthreads();

    float zr[16];
#pragma unroll
    for (int e = 0; e < 16; ++e) zr[e] = zt[r * 17 + e];
    float best = -1e30f; int bidx = 0;
    for (int cc = 0; cc < 16; ++cc) {
        int col = cc * 16 + c;
        float d = 0.f;
#pragma unroll
        for (int e4 = 0; e4 < 4; ++e4) {
            float4 wv = *(const float4*)&nwt[col * 20 + e4 * 4];
            d += zr[e4 * 4 + 0] * wv.x + zr[e4 * 4 + 1] * wv.y
               + zr[e4 * 4 + 2] * wv.z + zr[e4 * 4 + 3] * wv.w;
        }
        dt[r * 257 + col] = d;
        if (d > best || (d == best && col < bidx)) { best = d; bidx = col; }
    }
#pragma unroll
    for (int m = 1; m < 16; m <<= 1) {
        float ov = __shfl_xor(best, m, 64);
        int   oi = __shfl_xor(bidx, m, 64);
        if (ov > best || (ov == best && oi < bidx)) { best = ov; bidx = oi; }
    }

    float q = emb[bidx * 16 + c];
    outQ[(rowBase + r) * 16 + c] = q;
    float df = q - zacc;
    float part = df * df;
#pragma unroll
    for (int m = 1; m < 64; m <<= 1) part += __shfl_xor(part, m, 64);
    if ((t & 63) == 0) swred[t >> 6] = part;
    if (c == 0) {
        outIdx[rowBase + r] = (float)bidx;
        atomicAdd(&lcnt[bidx], 1);
    }
    __syncthreads();
    if (t == 0) atomicAdd(qsum, swred[0] + swred[1] + swred[2] + swred[3]);
    if (lcnt[t] > 0) atomicAdd(&counts[t], lcnt[t]);

    int rr = t & 15, cg = t >> 4;
    for (int i = 0; i < 16; ++i) {
        int col = i * 16 + cg;
        distT[(long)col * NROWS + rowBase + rr] = dt[rr * 257 + col];
    }
}

// ---------------------------------------------------------------------------
// SelA: per-column histogram; median bin and top-512 threshold bin.
// ---------------------------------------------------------------------------
__global__ __launch_bounds__(1024)
void selA_kernel(const float* __restrict__ distT, int* __restrict__ stats)
{
    __shared__ int hist[NB];
    __shared__ int part[1024];
    int t = threadIdx.x, c = blockIdx.x;
    for (int i = t; i < NB; i += 1024) hist[i] = 0;
    __syncthreads();
    const float* col = distT + (long)c * NROWS;
    for (int i = t; i < NROWS; i += 1024) {
        float v = col[i];
        int b = (int)((v + 1.0f) * (NB * 0.5f));
        b = min(max(b, 0), NB - 1);
        atomicAdd(&hist[b], 1);
    }
    __syncthreads();
    const int CH = NB / 1024;
    int s = 0;
    for (int i = 0; i < CH; ++i) s += hist[t * CH + i];
    part[t] = s;
    __syncthreads();
    if (t == 0) {
        int target = NROWS / 2;
        int cum = 0; int chunk = 0;
        while (cum + part[chunk] < target) { cum += part[chunk]; ++chunk; }
        int b = chunk * CH;
        while (cum + hist[b] < target) { cum += hist[b]; ++b; }
        int medBin = b, needLow = target - cum, cntMed = hist[b];
        int cumA = 0; chunk = 1023;
        while (cumA + part[chunk] < 512) { cumA += part[chunk]; --chunk; }
        b = chunk * CH + CH - 1;
        while (cumA + hist[b] < 512) { cumA += hist[b]; --b; }
        int topBin = b, needTop = 512 - cumA, cntTop = hist[b];
        int* st = stats + c * 6;
        st[0] = medBin; st[1] = needLow; st[2] = cntMed;
        st[3] = topBin; st[4] = needTop; st[5] = cntTop;
    }
}

// ---------------------------------------------------------------------------
// SelB: re-scan column; top-512 mean and logsumexp over bottom half.
// ---------------------------------------------------------------------------
__global__ __launch_bounds__(1024)
void selB_kernel(const float* __restrict__ distT, const int* __restrict__ stats,
                 float* __restrict__ contra_sum)
{
    __shared__ float red[64];
    int t = threadIdx.x, c = blockIdx.x;
    const int* st = stats + c * 6;
    int medBin = st[0], needLow = st[1], cntMed = st[2];
    int topBin = st[3], needTop = st[4], cntTop = st[5];
    const float binw = 2.0f / NB;
    float mUp = -1.0f + (medBin + 1) * binw;
    const float INVT = 1.0f / 0.07f;
    const float* col = distT + (long)c * NROWS;
    float topS = 0.f, tbS = 0.f, lowS = 0.f, mbS = 0.f;
    for (int i = t; i < NROWS; i += 1024) {
        float v = col[i];
        int b = (int)((v + 1.0f) * (NB * 0.5f));
        b = min(max(b, 0), NB - 1);
        if (b > topBin)       topS += v;
        else if (b == topBin) tbS += v;
        if (b < medBin)       lowS += expf((v - mUp) * INVT);
        else if (b == medBin) mbS  += expf((v - mUp) * INVT);
    }
#pragma unroll
    for (int m = 1; m < 64; m <<= 1) {
        topS += __shfl_xor(topS, m, 64);
        tbS  += __shfl_xor(tbS, m, 64);
        lowS += __shfl_xor(lowS, m, 64);
        mbS  += __shfl_xor(mbS, m, 64);
    }
    if ((t & 63) == 0) {
        int wv = t >> 6;
        red[wv * 4 + 0] = topS; red[wv * 4 + 1] = tbS;
        red[wv * 4 + 2] = lowS; red[wv * 4 + 3] = mbS;
    }
    __syncthreads();
    if (t == 0) {
        float T0 = 0, T1 = 0, T2 = 0, T3 = 0;
        for (int wv = 0; wv < 16; ++wv) {
            T0 += red[wv * 4 + 0]; T1 += red[wv * 4 + 1];
            T2 += red[wv * 4 + 2]; T3 += red[wv * 4 + 3];
        }
        float dis_pos = (T0 + needTop * (T1 / cntTop)) * (1.0f / 512.0f);
        float S = T2 + needLow * (T3 / cntMed);
        float colContra = log1pf(S * expf((mUp - dis_pos) * INVT));
        atomicAdd(contra_sum, colContra);
    }
}

// ---------------------------------------------------------------------------
// D3: reconstructed = d2 @ dec_w3 + b (d2 = hi + lo*2^-12), + recon loss.
// ---------------------------------------------------------------------------
__global__ __launch_bounds__(256)
void dec3_kernel(const ushort_t* __restrict__ d2hi, const ushort_t* __restrict__ d2lo,
                 const float* __restrict__ W,
                 const float* __restrict__ bias, const float* __restrict__ actions,
                 float* __restrict__ rec, float* __restrict__ recon_sum)
{
    __shared__ float dtile[16 * 516];
    __shared__ float wt[512 * 12];
    __shared__ float red2[4];
    int t = threadIdx.x;
    long rowBase = (long)blockIdx.x * 16;
    for (int it = 0; it < 24; ++it) wt[it * 256 + t] = W[it * 256 + t];
    for (int it = 0; it < 32; ++it) {
        int flat = it * 256 + t;
        int r = flat >> 9, k = flat & 511;
        long idx = (rowBase + r) * 512 + k;
        dtile[r * 516 + k] = f16pair(d2hi[idx], d2lo[idx]);
    }
    __syncthreads();
    float part = 0.f;
    if (t < 192) {
        int r = t / 12, cc = t % 12;
        float acc = bias[cc];
        for (int k4 = 0; k4 < 128; ++k4) {
            float4 h = *(const float4*)&dtile[r * 516 + k4 * 4];
            acc += h.x * wt[(k4 * 4 + 0) * 12 + cc] + h.y * wt[(k4 * 4 + 1) * 12 + cc]
                 + h.z * wt[(k4 * 4 + 2) * 12 + cc] + h.w * wt[(k4 * 4 + 3) * 12 + cc];
        }
        rec[(rowBase + r) * 12 + cc] = acc;
        float df = acc - actions[(rowBase + r) * 12 + cc];
        part = df * df;
    }
#pragma unroll
    for (int m = 1; m < 64; m <<= 1) part += __shfl_xor(part, m, 64);
    if ((t & 63) == 0) red2[t >> 6] = part;
    __syncthreads();
    if (t == 0) atomicAdd(recon_sum, red2[0] + red2[1] + red2[2] + red2[3]);
}

// ---------------------------------------------------------------------------
// finalize: perplexity from counts + scalar outputs.
// ---------------------------------------------------------------------------
__global__ void finalize_kernel(const int* __restrict__ counts, float* __restrict__ outScal)
{
    __shared__ float red[4];
    int t = threadIdx.x;
    float p = counts[t] * (1.0f / NROWS);
    float term = p * logf(p + 1e-10f);
#pragma unroll
    for (int m = 1; m < 64; m <<= 1) term += __shfl_xor(term, m, 64);
    if ((t & 63) == 0) red[t >> 6] = term;
    __syncthreads();
    if (t == 0) {
        float hsum = red[0] + red[1] + red[2] + red[3];
        float qsum = outScal[0], contra = outScal[2], recon = outScal[4];
        float ql = qsum * (1.0f / (NROWS * 16.0f));
        outScal[0] = ql;
        outScal[1] = 0.25f * ql;
        outScal[2] = contra * (1.0f / 256.0f);
        outScal[3] = expf(-hsum);
        outScal[4] = recon * (1.0f / (NROWS * 12.0f));
    }
}

extern "C" void kernel_launch(void* const* d_in, const int* in_sizes, int n_in,
                              void* d_out, int out_size, void* d_ws, size_t ws_size,
                              hipStream_t stream)
{
    const float* actions    = (const float*)d_in[0];
    const float* conditions = (const float*)d_in[1];
    const float* enc_w1 = (const float*)d_in[2];
    const float* enc_b1 = (const float*)d_in[3];
    const float* enc_w2 = (const float*)d_in[4];
    const float* enc_b2 = (const float*)d_in[5];
    const float* enc_w3 = (const float*)d_in[6];
    const float* enc_b3 = (const float*)d_in[7];
    const float* dec_w1 = (const float*)d_in[8];
    const float* dec_b1 = (const float*)d_in[9];
    const float* dec_w2 = (const float*)d_in[10];
    const float* dec_b2 = (const float*)d_in[11];
    const float* dec_w3 = (const float*)d_in[12];
    const float* dec_b3 = (const float*)d_in[13];
    const float* emb    = (const float*)d_in[14];

    float* out     = (float*)d_out;
    float* outRec  = out;
    float* outQ    = out + (long)NROWS * 12;
    float* outIdx  = out + (long)NROWS * 28;
    float* outScal = out + (long)NROWS * 29;

    // converted weights live in the (dead-until-dec3) outRec region
    ushort_t* wb    = (ushort_t*)d_out;
    ushort_t* w1hi  = wb;            ushort_t* w1lo  = wb + 147456;
    ushort_t* w2hi  = wb + 294912;   ushort_t* w2lo  = wb + 425984;
    ushort_t* wd1hi = wb + 557056;   ushort_t* wd1lo = wb + 630784;
    ushort_t* wd2hi = wb + 704512;   ushort_t* wd2lo = wb + 835584;

    float* ws = (float*)d_ws;
    int* counts = (int*)ws;
    int* stats  = (int*)(ws + 256);
    ushort_t* h2hi = (ushort_t*)(ws + 1792);
    ushort_t* h2lo = (ushort_t*)(ws + 16779008);
    ushort_t* d1hi = h2hi;
    ushort_t* d1lo = h2lo;
    float*    P1   = ws + 33556224;
    ushort_t* h1hi = (ushort_t*)P1;
    ushort_t* h1lo = (ushort_t*)(ws + 67110656);
    float*    distT = P1;
    ushort_t* d2hi = h1hi;
    ushort_t* d2lo = h1lo;

    hipLaunchKernelGGL(init_kernel, dim3(1), dim3(256), 0, stream, counts, outScal);
    hipLaunchKernelGGL(convw_kernel, dim3(512, 2), dim3(256), 0, stream, enc_w1, w1hi, w1lo, 268, 512, 288);
    hipLaunchKernelGGL(convw_kernel, dim3(256, 2), dim3(256), 0, stream, enc_w2, w2hi, w2lo, 512, 256, 512);
    hipLaunchKernelGGL(convw_kernel, dim3(256, 2), dim3(256), 0, stream, dec_w1, wd1hi, wd1lo, 272, 256, 288);
    hipLaunchKernelGGL(convw_kernel, dim3(512, 1), dim3(256), 0, stream, dec_w2, wd2hi, wd2lo, 256, 512, 256);
    // E1: h1 = elu(concat(actions,conditions) @ W1 + b1)  [v5 BK=32 schedule]
    hipLaunchKernelGGL((gemm_f16x3_kernel<ACT_D>), dim3(2048, 4), dim3(256), 0, stream,
                       (const void*)actions, (const void*)conditions, w1hi, w1lo, enc_b1,
                       h1hi, h1lo, H1D, 288, 268);
    // E2: h2 = elu(h1 @ W2 + b2)  [BK=64 rounds]
    hipLaunchKernelGGL((gemm_f16x3_kernel<0>), dim3(2048, 2), dim3(256), 0, stream,
                       (const void*)h1hi, (const void*)h1lo, w2hi, w2lo, enc_b2,
                       h2hi, h2lo, H2D, 512, 512);
    // K3: z, normalize, argmax, quantized, counts, q-latent, distT
    hipLaunchKernelGGL(quantize_kernel, dim3(8192), dim3(256), 0, stream,
                       h2hi, h2lo, enc_w3, enc_b3, emb, distT, outQ, outIdx, counts, &outScal[0]);
    hipLaunchKernelGGL(selA_kernel, dim3(256), dim3(1024), 0, stream, distT, stats);
    hipLaunchKernelGGL(selB_kernel, dim3(256), dim3(1024), 0, stream, distT, stats, &outScal[2]);
    // D1: d1 = elu(concat(quantized,conditions) @ Wd1 + b1)  [v5 BK=32 schedule]
    hipLaunchKernelGGL((gemm_f16x3_kernel<EDIM>), dim3(2048, 2), dim3(256), 0, stream,
                       (const void*)outQ, (const void*)conditions, wd1hi, wd1lo, dec_b1,
                       d1hi, d1lo, H2D, 288, 272);
    // D2: d2 = elu(d1 @ Wd2 + b2)  [BK=64 rounds]
    hipLaunchKernelGGL((gemm_f16x3_kernel<0>), dim3(2048, 4), dim3(256), 0, stream,
                       (const void*)d1hi, (const void*)d1lo, wd2hi, wd2lo, dec_b2,
                       d2hi, d2lo, H1D, 256, 256);
    // D3: reconstructed + loss
    hipLaunchKernelGGL(dec3_kernel, dim3(8192), dim3(256), 0, stream,
                       d2hi, d2lo, dec_w3, dec_b3, actions, outRec, &outScal[4]);
    hipLaunchKernelGGL(finalize_kernel, dim3(1), dim3(256), 0, stream, counts, outScal);
}